// Round 2
// baseline (234.677 us; speedup 1.0000x reference)
//
#include <hip/hip_runtime.h>

// LIF neuron over [T, B, C, H, W] = [8, 32, 128, 32, 32] fp32.
// V_new = V + (-V/TAU + x_t); spike = (V_new>=1) - (V_new<=-1); hard reset.
//
// R1 finding: load→vmcnt(0)→compute→store per unrolled iteration serialized
// one HBM latency (~900 cyc) per timestep per wave → 3.3 TB/s effective.
// R2: hoist all 8 timestep loads up front (8 outstanding dwordx4 per wave),
// then compute+store. VGPR ~55, still 8 waves/SIMD.

#define T_STEPS 8

__device__ __forceinline__ float lif_step(float& V, float x) {
    const float TAU = (float)(5.0 / 3.0);  // fp32, matches np cast
    // Replicate reference op order exactly: neg, IEEE divide, add, add.
    float dv = (-V) / TAU + x;
    float Vn = V + dv;
    float o = (Vn >= 1.0f ? 1.0f : 0.0f) - (Vn <= -1.0f ? 1.0f : 0.0f);
    V = (o == 0.0f) ? Vn : 0.0f;  // o is exactly -1/0/+1
    return o;
}

__global__ __launch_bounds__(256) void lif_kernel(const float4* __restrict__ x,
                                                  float4* __restrict__ out,
                                                  int n4) {
    int i = blockIdx.x * blockDim.x + threadIdx.x;
    if (i >= n4) return;

    // Stage all T loads first: 8 outstanding global_load_dwordx4 per lane.
    float4 xt[T_STEPS];
#pragma unroll
    for (int t = 0; t < T_STEPS; ++t) {
        xt[t] = x[(size_t)t * n4 + i];
    }

    float4 V = make_float4(0.f, 0.f, 0.f, 0.f);
#pragma unroll
    for (int t = 0; t < T_STEPS; ++t) {
        float4 o;
        o.x = lif_step(V.x, xt[t].x);
        o.y = lif_step(V.y, xt[t].y);
        o.z = lif_step(V.z, xt[t].z);
        o.w = lif_step(V.w, xt[t].w);
        out[(size_t)t * n4 + i] = o;
    }
}

extern "C" void kernel_launch(void* const* d_in, const int* in_sizes, int n_in,
                              void* d_out, int out_size, void* d_ws, size_t ws_size,
                              hipStream_t stream) {
    const float* x = (const float*)d_in[0];
    float* out = (float*)d_out;

    int total = in_sizes[0];            // T*B*C*H*W = 33554432
    int n = total / T_STEPS;            // spatial elements per timestep
    int n4 = n / 4;                     // float4 groups

    dim3 block(256);
    dim3 grid((n4 + block.x - 1) / block.x);
    lif_kernel<<<grid, block, 0, stream>>>((const float4*)x, (float4*)out, n4);
}

// Round 3
// 233.932 us; speedup vs baseline: 1.0032x; 1.0032x over previous
//
#include <hip/hip_runtime.h>

// LIF neuron over [T, B, C, H, W] = [8, 32, 128, 32, 32] fp32.
// V_new = V + (-V/TAU + x_t); spike = (V_new>=1) - (V_new<=-1); hard reset.
//
// R1: per-t load->vmcnt(0)->compute->store serialized one HBM latency per
// timestep (3.3 TB/s effective). R2: source-level hoist was re-sunk by the
// max-occupancy scheduler (VGPR stayed 24). R3: hard scheduling fence
// (asm memory clobber) between the 8 loads and the compute loop -> all 8
// global_load_dwordx4 issue back-to-back, 8 KB in flight per wave.

#define T_STEPS 8

__device__ __forceinline__ float lif_step(float& V, float x) {
    const float TAU = (float)(5.0 / 3.0);  // fp32, matches np cast
    // Replicate reference op order exactly: neg, IEEE divide, add, add.
    float dv = (-V) / TAU + x;
    float Vn = V + dv;
    float o = (Vn >= 1.0f ? 1.0f : 0.0f) - (Vn <= -1.0f ? 1.0f : 0.0f);
    V = (o == 0.0f) ? Vn : 0.0f;  // o is exactly -1/0/+1
    return o;
}

__device__ __forceinline__ float4 lif_step4(float4& V, float4 xt) {
    float4 o;
    o.x = lif_step(V.x, xt.x);
    o.y = lif_step(V.y, xt.y);
    o.z = lif_step(V.z, xt.z);
    o.w = lif_step(V.w, xt.w);
    return o;
}

__global__ __launch_bounds__(256) void lif_kernel(const float4* __restrict__ x,
                                                  float4* __restrict__ out,
                                                  int n4) {
    int i = blockIdx.x * blockDim.x + threadIdx.x;
    if (i >= n4) return;

    const size_t s = (size_t)n4;
    // Issue all 8 timestep loads back-to-back (8 outstanding dwordx4/lane).
    float4 x0 = x[0 * s + i];
    float4 x1 = x[1 * s + i];
    float4 x2 = x[2 * s + i];
    float4 x3 = x[3 * s + i];
    float4 x4 = x[4 * s + i];
    float4 x5 = x[5 * s + i];
    float4 x6 = x[6 * s + i];
    float4 x7 = x[7 * s + i];

    // Hard scheduling fence: loads may not sink below, stores may not rise
    // above. Forces all 8 loads in flight before the first vmcnt wait.
    asm volatile("" ::: "memory");

    float4 V = make_float4(0.f, 0.f, 0.f, 0.f);
    out[0 * s + i] = lif_step4(V, x0);
    out[1 * s + i] = lif_step4(V, x1);
    out[2 * s + i] = lif_step4(V, x2);
    out[3 * s + i] = lif_step4(V, x3);
    out[4 * s + i] = lif_step4(V, x4);
    out[5 * s + i] = lif_step4(V, x5);
    out[6 * s + i] = lif_step4(V, x6);
    out[7 * s + i] = lif_step4(V, x7);
}

extern "C" void kernel_launch(void* const* d_in, const int* in_sizes, int n_in,
                              void* d_out, int out_size, void* d_ws, size_t ws_size,
                              hipStream_t stream) {
    const float* x = (const float*)d_in[0];
    float* out = (float*)d_out;

    int total = in_sizes[0];            // T*B*C*H*W = 33554432
    int n = total / T_STEPS;            // spatial elements per timestep
    int n4 = n / 4;                     // float4 groups

    dim3 block(256);
    dim3 grid((n4 + block.x - 1) / block.x);
    lif_kernel<<<grid, block, 0, stream>>>((const float4*)x, (float4*)out, n4);
}

// Round 6
// 221.355 us; speedup vs baseline: 1.0602x; 1.0568x over previous
//
#include <hip/hip_runtime.h>

// LIF neuron over [T, B, C, H, W] = [8, 32, 128, 32, 32] fp32.
// V_new = V + (-V/TAU + x_t); spike = (V_new>=1) - (V_new<=-1); hard reset.
//
// R1-R3: single-chain version pinned at 82 us / 2.4 TB/s regardless of
// scheduling hints (VGPR stuck at 24 -> loads never concurrently live).
// R4: structural MLP — each thread owns 4 independent columns (strided by
// Q = n4/4, wave-contiguous). Per timestep the 4 column loads issue
// back-to-back in one basic block -> 4 outstanding loads + 4 stores per
// wave guaranteed by the compiler's own precise vmcnt waits. Nontemporal
// ld/st: zero-reuse stream, don't thrash L2/L3.
// R5: __builtin_nontemporal_* requires clang ext_vector_type.
// R6: ext_vector elements can't bind to float& — value-in/value-out step.

#define T_STEPS 8

typedef float vfloat4 __attribute__((ext_vector_type(4)));

struct StepOut { float V; float o; };

__device__ __forceinline__ StepOut lif_step(float V, float x) {
    const float TAU = (float)(5.0 / 3.0);  // fp32, matches np cast
    // Replicate reference op order exactly: neg, IEEE divide, add, add.
    float dv = (-V) / TAU + x;
    float Vn = V + dv;
    float o = (Vn >= 1.0f ? 1.0f : 0.0f) - (Vn <= -1.0f ? 1.0f : 0.0f);
    StepOut r;
    r.o = o;
    r.V = (o == 0.0f) ? Vn : 0.0f;  // o is exactly -1/0/+1
    return r;
}

__device__ __forceinline__ vfloat4 lif_step4(vfloat4& V, vfloat4 xt) {
    StepOut a = lif_step(V.x, xt.x);
    StepOut b = lif_step(V.y, xt.y);
    StepOut c = lif_step(V.z, xt.z);
    StepOut d = lif_step(V.w, xt.w);
    vfloat4 Vn, o;
    Vn.x = a.V; Vn.y = b.V; Vn.z = c.V; Vn.w = d.V;
    o.x = a.o;  o.y = b.o;  o.z = c.o;  o.w = d.o;
    V = Vn;
    return o;
}

__global__ __launch_bounds__(256) void lif_kernel(const vfloat4* __restrict__ x,
                                                  vfloat4* __restrict__ out,
                                                  int n4) {
    const int Q = n4 >> 2;  // columns per chain-slot (n4 divisible by 4)
    int q = blockIdx.x * blockDim.x + threadIdx.x;
    if (q >= Q) return;

    const size_t s = (size_t)n4;
    const size_t i0 = (size_t)q;
    const size_t i1 = (size_t)q + (size_t)Q;
    const size_t i2 = (size_t)q + 2 * (size_t)Q;
    const size_t i3 = (size_t)q + 3 * (size_t)Q;

    vfloat4 Va = (vfloat4)(0.f);
    vfloat4 Vb = Va, Vc = Va, Vd = Va;

#pragma unroll
    for (int t = 0; t < T_STEPS; ++t) {
        const size_t base = (size_t)t * s;
        // 4 independent loads issued back-to-back (4 outstanding/wave min).
        vfloat4 xa = __builtin_nontemporal_load(&x[base + i0]);
        vfloat4 xb = __builtin_nontemporal_load(&x[base + i1]);
        vfloat4 xc = __builtin_nontemporal_load(&x[base + i2]);
        vfloat4 xd = __builtin_nontemporal_load(&x[base + i3]);

        vfloat4 oa = lif_step4(Va, xa);
        vfloat4 ob = lif_step4(Vb, xb);
        vfloat4 oc = lif_step4(Vc, xc);
        vfloat4 od = lif_step4(Vd, xd);

        __builtin_nontemporal_store(oa, &out[base + i0]);
        __builtin_nontemporal_store(ob, &out[base + i1]);
        __builtin_nontemporal_store(oc, &out[base + i2]);
        __builtin_nontemporal_store(od, &out[base + i3]);
    }
}

extern "C" void kernel_launch(void* const* d_in, const int* in_sizes, int n_in,
                              void* d_out, int out_size, void* d_ws, size_t ws_size,
                              hipStream_t stream) {
    const float* x = (const float*)d_in[0];
    float* out = (float*)d_out;

    int total = in_sizes[0];            // T*B*C*H*W = 33554432
    int n = total / T_STEPS;            // spatial elements per timestep
    int n4 = n / 4;                     // float4 groups = 1048576
    int Q = n4 / 4;                     // threads = 262144

    dim3 block(256);
    dim3 grid((Q + block.x - 1) / block.x);  // 1024 blocks
    lif_kernel<<<grid, block, 0, stream>>>((const vfloat4*)x, (vfloat4*)out, n4);
}